// Round 4
// baseline (546.480 us; speedup 1.0000x reference)
//
#include <hip/hip_runtime.h>

#define VERTS   100000
#define NCLUST  25000
#define BATCH_N 1024
#define THREADS 1024

typedef float  f32x4 __attribute__((ext_vector_type(4)));
typedef int    i32x4 __attribute__((ext_vector_type(4)));

// out[b, v] = x[b, v2c[v]]
// R0 structure (twice-verified) + dual-pipe gather split.
// The per-CU floor is the LDS pipe: 25000 wave-level ds_read_b32 with random
// ~5-way bank conflicts ~= 135us/CU. LDS and VMEM are separate pipes, so 1/3
// of gather iterations instead load directly from the x row, which is L2-hot:
// staging uses PLAIN loads (warms per-XCD L2; 32 blocks x 100KB = 3.2MB +
// 400KB v2c < 4MB), and out stores stay NONTEMPORAL so the 400MB out stream
// does not evict the x rows from L2. Branch is wave-uniform (k = q>>10).
__global__ __launch_bounds__(THREADS) void gather_split_kernel(
    const float* __restrict__ x,     // [BATCH_N, NCLUST]
    const int*   __restrict__ v2c,   // [VERTS]
    float*       __restrict__ out)   // [BATCH_N, VERTS]
{
    extern __shared__ float lds[];   // NCLUST floats = 100000 bytes
    const int b   = blockIdx.x;
    const int tid = threadIdx.x;

    const float* __restrict__ xrow = x + (size_t)b * NCLUST;

    // Phase 1: coalesced float4 staging into LDS, PLAIN loads (populate L2).
    const f32x4* __restrict__ xrow4 = reinterpret_cast<const f32x4*>(xrow);
    f32x4* lds4 = reinterpret_cast<f32x4*>(lds);
    for (int i = tid; i < NCLUST / 4; i += THREADS) {
        lds4[i] = xrow4[i];
    }
    __syncthreads();

    // Phase 2: int4 idx load (L2-hit); gather via LDS pipe (k%3 != 2) or
    // VMEM pipe from the L2-resident row (k%3 == 2); float4 nt store.
    const i32x4* __restrict__ v2c4 = reinterpret_cast<const i32x4*>(v2c);
    f32x4* __restrict__ out4 =
        reinterpret_cast<f32x4*>(out + (size_t)b * VERTS);
    for (int q = tid; q < VERTS / 4; q += THREADS) {
        const i32x4 idx = v2c4[q];
        const int k = q >> 10;           // iteration index, wave-uniform
        f32x4 o;
        if ((k % 3) == 2) {              // VMEM-pipe gather (L2-hit)
            o.x = xrow[idx.x];
            o.y = xrow[idx.y];
            o.z = xrow[idx.z];
            o.w = xrow[idx.w];
        } else {                         // LDS-pipe gather
            o.x = lds[idx.x];
            o.y = lds[idx.y];
            o.z = lds[idx.z];
            o.w = lds[idx.w];
        }
        __builtin_nontemporal_store(o, &out4[q]);
    }
}

extern "C" void kernel_launch(void* const* d_in, const int* in_sizes, int n_in,
                              void* d_out, int out_size, void* d_ws, size_t ws_size,
                              hipStream_t stream) {
    const float* x   = (const float*)d_in[0];   // [1024, 25000] f32
    const int*   v2c = (const int*)d_in[1];     // [100000] i32
    float*       out = (float*)d_out;           // [1024, 100000] f32

    const int lds_bytes = NCLUST * (int)sizeof(float);  // 100000 B > 64 KB default cap
    static bool attr_set = false;  // idempotent host-side attribute, not a stream op
    if (!attr_set) {
        hipFuncSetAttribute(reinterpret_cast<const void*>(gather_split_kernel),
                            hipFuncAttributeMaxDynamicSharedMemorySize, lds_bytes);
        attr_set = true;
    }

    gather_split_kernel<<<BATCH_N, THREADS, lds_bytes, stream>>>(x, v2c, out);
}